// Round 1
// 2779.366 us; speedup vs baseline: 1.5518x; 1.5518x over previous
//
#include <hip/hip_runtime.h>
#include <cstdint>

#define NB 4
#define NSEQ 1024
#define DMODEL 768
#define NHEAD 12
#define DHEAD 64
#define NDEPTH 6
#define DFF 3072
#define MROWS (NB * NSEQ)   // 4096

// weight block element offsets (concatenated wq|wk|wv|wo|wi|wof per layer)
#define WQ_OFF 0L
#define WK_OFF 589824L
#define WV_OFF 1179648L
#define WO_OFF 1769472L
#define WI_OFF 2359296L
#define WOF_OFF 4718592L
#define WTOT 7077888L

typedef __attribute__((ext_vector_type(8))) short short8;
typedef __attribute__((ext_vector_type(4))) float floatx4;

static __device__ __forceinline__ float b2f(unsigned short u) {
  union { unsigned int i; float f; } v; v.i = ((unsigned int)u) << 16; return v.f;
}
static __device__ __forceinline__ unsigned short f2b(float f) {
  union { float f; unsigned int i; } v; v.f = f;
  unsigned int x = v.i;
  return (unsigned short)((x + 0x7fffu + ((x >> 16) & 1u)) >> 16);  // RNE
}
// split f32 -> (hi, lo) bf16 pair; hi+lo reconstructs to ~2^-17 rel
static __device__ __forceinline__ void fsplit(float f, unsigned short& h, unsigned short& l) {
  h = f2b(f);
  l = f2b(f - b2f(h));
}

// ---------------- per-layer weight split f32 -> hi/lo bf16
__global__ __launch_bounds__(256) void wsplit_kernel(
    const float* __restrict__ wq, const float* __restrict__ wk,
    const float* __restrict__ wv, const float* __restrict__ wo,
    const float* __restrict__ wi, const float* __restrict__ wof,
    unsigned short* __restrict__ dhi, unsigned short* __restrict__ dlo)
{
  long i = ((long)blockIdx.x * 256 + threadIdx.x) * 4;
  if (i >= WTOT) return;
  const float* src; long off;
  if (i < WK_OFF)       { src = wq;  off = i - WQ_OFF; }
  else if (i < WV_OFF)  { src = wk;  off = i - WK_OFF; }
  else if (i < WO_OFF)  { src = wv;  off = i - WV_OFF; }
  else if (i < WI_OFF)  { src = wo;  off = i - WO_OFF; }
  else if (i < WOF_OFF) { src = wi;  off = i - WI_OFF; }
  else                  { src = wof; off = i - WOF_OFF; }
  float4 f = *(const float4*)(src + off);
  ushort4 h, l;
  fsplit(f.x, h.x, l.x); fsplit(f.y, h.y, l.y);
  fsplit(f.z, h.z, l.z); fsplit(f.w, h.w, l.w);
  *(ushort4*)(dhi + i) = h;
  *(ushort4*)(dlo + i) = l;
}

// ---------------- embedding gather -> split x
__global__ void embed_kernel(const int* __restrict__ tok,
                             const float* __restrict__ emb,
                             unsigned short* __restrict__ xhi,
                             unsigned short* __restrict__ xlo) {
  const int row = blockIdx.x;
  const int t = tok[row];
  const float* src = emb + (long)t * DMODEL;
  for (int d = threadIdx.x; d < DMODEL; d += 256) {
    unsigned short h, l;
    fsplit(src[d], h, l);
    xhi[(long)row * DMODEL + d] = h;
    xlo[(long)row * DMODEL + d] = l;
  }
}

// ---------------- GEMM: C(MxN) = act(alpha * A(MxK) @ W(NxK)^T [+ resid])
// All operands split hi/lo bf16. D = Ah*Wh + Al*Wh + Ah*Wl (lo*lo dropped, ~2^-18).
// 64x64 block tile, 4 waves in 2x2, each wave 32x32 (2x2 of 16x16 MFMA).
template<int RELU, int RESID>
__global__ __launch_bounds__(256) void gemm_bt(
    const unsigned short* __restrict__ Ahi, const unsigned short* __restrict__ Alo,
    const unsigned short* __restrict__ Whi, const unsigned short* __restrict__ Wlo,
    unsigned short* __restrict__ Chi, unsigned short* __restrict__ Clo,
    const unsigned short* __restrict__ Rhi, const unsigned short* __restrict__ Rlo,
    int M, int N, int K, float alpha)
{
  __shared__ unsigned short sAh[64][40];  // +8 pad: 2-way bank alias only (free)
  __shared__ unsigned short sAl[64][40];
  __shared__ unsigned short sBh[64][40];
  __shared__ unsigned short sBl[64][40];

  const int tid = threadIdx.x;
  const int bn = blockIdx.x, bm = blockIdx.y;
  const int srow = tid >> 2;         // 0..63 staging row
  const int skc  = (tid & 3) << 3;   // 0,8,16,24 staging k-offset
  const int wave = tid >> 6;
  const int lane = tid & 63;
  const int wm = wave >> 1, wn = wave & 1;
  const int l16 = lane & 15, q4 = lane >> 4;

  floatx4 acc[2][2];
  #pragma unroll
  for (int i = 0; i < 2; ++i)
    #pragma unroll
    for (int j = 0; j < 2; ++j) {
      floatx4 z = {0.f, 0.f, 0.f, 0.f};
      acc[i][j] = z;
    }

  const long arow = (long)(bm * 64 + srow) * K;
  const long brow = (long)(bn * 64 + srow) * K;

  for (int k0 = 0; k0 < K; k0 += 32) {
    *(short8*)&sAh[srow][skc] = *(const short8*)(Ahi + arow + k0 + skc);
    *(short8*)&sAl[srow][skc] = *(const short8*)(Alo + arow + k0 + skc);
    *(short8*)&sBh[srow][skc] = *(const short8*)(Whi + brow + k0 + skc);
    *(short8*)&sBl[srow][skc] = *(const short8*)(Wlo + brow + k0 + skc);
    __syncthreads();

    short8 a0h = *(const short8*)&sAh[wm * 32 +      l16][q4 * 8];
    short8 a1h = *(const short8*)&sAh[wm * 32 + 16 + l16][q4 * 8];
    short8 a0l = *(const short8*)&sAl[wm * 32 +      l16][q4 * 8];
    short8 a1l = *(const short8*)&sAl[wm * 32 + 16 + l16][q4 * 8];
    short8 b0h = *(const short8*)&sBh[wn * 32 +      l16][q4 * 8];
    short8 b1h = *(const short8*)&sBh[wn * 32 + 16 + l16][q4 * 8];
    short8 b0l = *(const short8*)&sBl[wn * 32 +      l16][q4 * 8];
    short8 b1l = *(const short8*)&sBl[wn * 32 + 16 + l16][q4 * 8];

    acc[0][0] = __builtin_amdgcn_mfma_f32_16x16x32_bf16(a0h, b0h, acc[0][0], 0, 0, 0);
    acc[0][1] = __builtin_amdgcn_mfma_f32_16x16x32_bf16(a0h, b1h, acc[0][1], 0, 0, 0);
    acc[1][0] = __builtin_amdgcn_mfma_f32_16x16x32_bf16(a1h, b0h, acc[1][0], 0, 0, 0);
    acc[1][1] = __builtin_amdgcn_mfma_f32_16x16x32_bf16(a1h, b1h, acc[1][1], 0, 0, 0);
    acc[0][0] = __builtin_amdgcn_mfma_f32_16x16x32_bf16(a0l, b0h, acc[0][0], 0, 0, 0);
    acc[0][1] = __builtin_amdgcn_mfma_f32_16x16x32_bf16(a0l, b1h, acc[0][1], 0, 0, 0);
    acc[1][0] = __builtin_amdgcn_mfma_f32_16x16x32_bf16(a1l, b0h, acc[1][0], 0, 0, 0);
    acc[1][1] = __builtin_amdgcn_mfma_f32_16x16x32_bf16(a1l, b1h, acc[1][1], 0, 0, 0);
    acc[0][0] = __builtin_amdgcn_mfma_f32_16x16x32_bf16(a0h, b0l, acc[0][0], 0, 0, 0);
    acc[0][1] = __builtin_amdgcn_mfma_f32_16x16x32_bf16(a0h, b1l, acc[0][1], 0, 0, 0);
    acc[1][0] = __builtin_amdgcn_mfma_f32_16x16x32_bf16(a1h, b0l, acc[1][0], 0, 0, 0);
    acc[1][1] = __builtin_amdgcn_mfma_f32_16x16x32_bf16(a1h, b1l, acc[1][1], 0, 0, 0);
    __syncthreads();
  }

  // epilogue: C/D layout col=lane&15, row=(lane>>4)*4+reg  [m89/m91 verified]
  #pragma unroll
  for (int mt = 0; mt < 2; ++mt) {
    #pragma unroll
    for (int nt = 0; nt < 2; ++nt) {
      const int r0 = bm * 64 + wm * 32 + mt * 16 + q4 * 4;
      const int c  = bn * 64 + wn * 32 + nt * 16 + l16;
      #pragma unroll
      for (int r = 0; r < 4; ++r) {
        float vv = acc[mt][nt][r] * alpha;
        const long idx = (long)(r0 + r) * N + c;
        if (RESID) vv += b2f(Rhi[idx]) + b2f(Rlo[idx]);
        if (RELU)  vv = fmaxf(vv, 0.f);
        unsigned short h, l;
        fsplit(vv, h, l);
        Chi[idx] = h; Clo[idx] = l;
      }
    }
  }
}

// ---------------- flash attention, MFMA path (mask all-ones -> ignored).
// Block = 64 query rows of one (b,h); 4 waves, each wave owns 16 rows.
// Online softmax in registers; hi/lo bf16 3-term MFMA for QK^T and PV.
// Fragment conventions identical to gemm_bt (harness-verified):
//   A/B frag: lane holds [row=lane&15][k=(lane>>4)*8+j], j=0..7
//   C/D:      col=lane&15, row=(lane>>4)*4+reg
__global__ __launch_bounds__(256) void attn_kernel(
    const unsigned short* __restrict__ qhi, const unsigned short* __restrict__ qlo,
    const unsigned short* __restrict__ khi, const unsigned short* __restrict__ klo,
    const unsigned short* __restrict__ vhi, const unsigned short* __restrict__ vlo,
    unsigned short* __restrict__ ohi, unsigned short* __restrict__ olo)
{
  // K chunk row-major [key][dh]; V chunk transposed [dh][key] with XOR-8 col
  // swizzle (keeps transpose writes conflict-free, reads 16B-aligned);
  // P per-wave [q][key]. Stride 72 ushorts = 144B (16B-aligned rows).
  __shared__ unsigned short ks_h[64][72];
  __shared__ unsigned short ks_l[64][72];
  __shared__ unsigned short vt_h[64][72];
  __shared__ unsigned short vt_l[64][72];
  __shared__ unsigned short ps_h[64][72];
  __shared__ unsigned short ps_l[64][72];

  const int tid = threadIdx.x;
  const int iq = blockIdx.x, h = blockIdx.y, b = blockIdx.z;
  const int wave = tid >> 6, lane = tid & 63;
  const int l16 = lane & 15, g4 = lane >> 4;
  const long base = ((long)b * NSEQ) * DMODEL + h * DHEAD;
  const int q0 = iq * 64;

  // Q fragments straight from global (A-frag layout is contiguous in memory)
  short8 qh[2], ql[2];
  {
    const long qr = base + (long)(q0 + wave * 16 + l16) * DMODEL + g4 * 8;
    qh[0] = *(const short8*)(qhi + qr);
    qh[1] = *(const short8*)(qhi + qr + 32);
    ql[0] = *(const short8*)(qlo + qr);
    ql[1] = *(const short8*)(qlo + qr + 32);
  }

  floatx4 oacc[4];
  #pragma unroll
  for (int nt = 0; nt < 4; ++nt) { floatx4 z = {0.f,0.f,0.f,0.f}; oacc[nt] = z; }
  float mrow[4] = {-INFINITY, -INFINITY, -INFINITY, -INFINITY};
  float lrow[4] = {0.f, 0.f, 0.f, 0.f};

  const int skey = tid >> 3;          // 0..31 staging key
  const int sd0  = (tid & 7) * 8;     // 0..56 staging dh offset

  for (int jc = 0; jc < NSEQ / 64; ++jc) {
    const int j0 = jc * 64;
    if (jc) __syncthreads();   // protect ks/vt from overwrite while still read

    // ---- stage K (row-major) and V (transposed, swizzled) hi/lo
    #pragma unroll
    for (int half = 0; half < 2; ++half) {
      const int key = skey + half * 32;
      const long off = base + (long)(j0 + key) * DMODEL + sd0;
      short8 kh8 = *(const short8*)(khi + off);
      short8 kl8 = *(const short8*)(klo + off);
      short8 vh8 = *(const short8*)(vhi + off);
      short8 vl8 = *(const short8*)(vlo + off);
      *(short8*)&ks_h[key][sd0] = kh8;
      *(short8*)&ks_l[key][sd0] = kl8;
      #pragma unroll
      for (int u = 0; u < 8; ++u) {
        const int dh = sd0 + u;
        const int cc = key ^ ((dh >> 3) << 3);   // spread banks across dh-groups
        vt_h[dh][cc] = (unsigned short)vh8[u];
        vt_l[dh][cc] = (unsigned short)vl8[u];
      }
    }
    __syncthreads();

    // ---- S = Q @ K^T   (16q x 64key per wave; 4 n-tiles)
    floatx4 sacc[4];
    #pragma unroll
    for (int nt = 0; nt < 4; ++nt) { floatx4 z = {0.f,0.f,0.f,0.f}; sacc[nt] = z; }
    #pragma unroll
    for (int nt = 0; nt < 4; ++nt) {
      #pragma unroll
      for (int ks = 0; ks < 2; ++ks) {
        short8 kh8 = *(const short8*)&ks_h[nt * 16 + l16][ks * 32 + g4 * 8];
        short8 kl8 = *(const short8*)&ks_l[nt * 16 + l16][ks * 32 + g4 * 8];
        sacc[nt] = __builtin_amdgcn_mfma_f32_16x16x32_bf16(qh[ks], kh8, sacc[nt], 0, 0, 0);
        sacc[nt] = __builtin_amdgcn_mfma_f32_16x16x32_bf16(ql[ks], kh8, sacc[nt], 0, 0, 0);
        sacc[nt] = __builtin_amdgcn_mfma_f32_16x16x32_bf16(qh[ks], kl8, sacc[nt], 0, 0, 0);
      }
    }

    // ---- online softmax; row r lives on the 16 lanes sharing g4
    float mx[4], al[4];
    #pragma unroll
    for (int r = 0; r < 4; ++r) {
      float m0 = fmaxf(fmaxf(sacc[0][r], sacc[1][r]), fmaxf(sacc[2][r], sacc[3][r]));
      m0 = fmaxf(m0, __shfl_xor(m0, 1));
      m0 = fmaxf(m0, __shfl_xor(m0, 2));
      m0 = fmaxf(m0, __shfl_xor(m0, 4));
      m0 = fmaxf(m0, __shfl_xor(m0, 8));
      const float mn = fmaxf(mrow[r], m0);
      al[r] = __expf(mrow[r] - mn);   // first chunk: exp(-inf)=0
      mrow[r] = mn;
      mx[r] = mn;
    }
    #pragma unroll
    for (int r = 0; r < 4; ++r) {
      const int qrow = wave * 16 + g4 * 4 + r;
      float rs = 0.f;
      #pragma unroll
      for (int nt = 0; nt < 4; ++nt) {
        const float p = __expf(sacc[nt][r] - mx[r]);
        rs += p;
        unsigned short ph, pl;
        fsplit(p, ph, pl);
        ps_h[qrow][nt * 16 + l16] = ph;
        ps_l[qrow][nt * 16 + l16] = pl;
      }
      rs += __shfl_xor(rs, 1);
      rs += __shfl_xor(rs, 2);
      rs += __shfl_xor(rs, 4);
      rs += __shfl_xor(rs, 8);
      lrow[r] = lrow[r] * al[r] + rs;
      oacc[0][r] *= al[r]; oacc[1][r] *= al[r];
      oacc[2][r] *= al[r]; oacc[3][r] *= al[r];
    }
    __syncthreads();   // P visible (also orders vt reads after stage writes)

    // ---- O += P @ V   (A = P from LDS, B = V^T fragments)
    #pragma unroll
    for (int ks = 0; ks < 2; ++ks) {
      short8 ph8 = *(const short8*)&ps_h[wave * 16 + l16][ks * 32 + g4 * 8];
      short8 pl8 = *(const short8*)&ps_l[wave * 16 + l16][ks * 32 + g4 * 8];
      #pragma unroll
      for (int nt = 0; nt < 4; ++nt) {
        const int dh = nt * 16 + l16;
        const int cb = (ks * 32 + g4 * 8) ^ ((dh >> 3) << 3);
        short8 vh8 = *(const short8*)&vt_h[dh][cb];
        short8 vl8 = *(const short8*)&vt_l[dh][cb];
        oacc[nt] = __builtin_amdgcn_mfma_f32_16x16x32_bf16(ph8, vh8, oacc[nt], 0, 0, 0);
        oacc[nt] = __builtin_amdgcn_mfma_f32_16x16x32_bf16(pl8, vh8, oacc[nt], 0, 0, 0);
        oacc[nt] = __builtin_amdgcn_mfma_f32_16x16x32_bf16(ph8, vl8, oacc[nt], 0, 0, 0);
      }
    }
  }

  // ---- epilogue: O / l, split-store
  const long orbase = base + (long)(q0 + wave * 16 + g4 * 4) * DMODEL;
  #pragma unroll
  for (int r = 0; r < 4; ++r) {
    const float inv = 1.f / lrow[r];
    #pragma unroll
    for (int nt = 0; nt < 4; ++nt) {
      unsigned short hh, ll;
      fsplit(oacc[nt][r] * inv, hh, ll);
      const long idx = orbase + (long)r * DMODEL + nt * 16 + l16;
      ohi[idx] = hh; olo[idx] = ll;
    }
  }
}

// ---------------- final T5 RMS layernorm, split in -> f32 out
__global__ __launch_bounds__(256) void ln_kernel(const unsigned short* __restrict__ xhi,
                                                 const unsigned short* __restrict__ xlo,
                                                 const float* __restrict__ w,
                                                 float* __restrict__ out)
{
  __shared__ float red[256];
  const int row = blockIdx.x;
  const long rb = (long)row * DMODEL;
  float ss = 0.f;
  for (int d = threadIdx.x; d < DMODEL; d += 256) {
    float v = b2f(xhi[rb + d]) + b2f(xlo[rb + d]);
    ss += v * v;
  }
  red[threadIdx.x] = ss;
  __syncthreads();
  for (int s = 128; s > 0; s >>= 1) {
    if (threadIdx.x < s) red[threadIdx.x] += red[threadIdx.x + s];
    __syncthreads();
  }
  const float rs = rsqrtf(red[0] * (1.f / DMODEL) + 1e-6f);
  for (int d = threadIdx.x; d < DMODEL; d += 256) {
    float v = b2f(xhi[rb + d]) + b2f(xlo[rb + d]);
    out[rb + d] = w[d] * v * rs;
  }
}

extern "C" void kernel_launch(void* const* d_in, const int* in_sizes, int n_in,
                              void* d_out, int out_size, void* d_ws, size_t ws_size,
                              hipStream_t stream)
{
  const int* tokens   = (const int*)d_in[0];
  // d_in[1] = mask (all ones in this problem) — unused
  const float* emb    = (const float*)d_in[2];
  const float* wq     = (const float*)d_in[3];
  const float* wk     = (const float*)d_in[4];
  const float* wv     = (const float*)d_in[5];
  const float* wo     = (const float*)d_in[6];
  const float* wi     = (const float*)d_in[7];
  const float* wof    = (const float*)d_in[8];
  const float* lnw    = (const float*)d_in[9];

  // ws layout (all ushort arrays, sizes in bytes):
  //   x_hi,x_lo              2 x 6.29MB
  //   act block q/k/v/o hi+lo 8 x 6.29MB  (reused as ff1_hi/ff1_lo, 2 x 25.2MB)
  //   w_hi,w_lo              2 x 14.2MB
  const size_t AS = (size_t)MROWS * DMODEL;   // 3,145,728 elems
  char* p = (char*)d_ws;
  unsigned short* xhi = (unsigned short*)p;  p += AS * 2;
  unsigned short* xlo = (unsigned short*)p;  p += AS * 2;
  unsigned short* act = (unsigned short*)p;  p += AS * 2 * 8;
  unsigned short* whi = (unsigned short*)p;  p += (size_t)WTOT * 2;
  unsigned short* wlo = (unsigned short*)p;  p += (size_t)WTOT * 2;

  unsigned short* qhi = act + AS * 0; unsigned short* qlo = act + AS * 1;
  unsigned short* khi = act + AS * 2; unsigned short* klo = act + AS * 3;
  unsigned short* vhi = act + AS * 4; unsigned short* vlo = act + AS * 5;
  unsigned short* ohi = act + AS * 6; unsigned short* olo = act + AS * 7;
  unsigned short* fhi = act + AS * 0; unsigned short* flo = act + AS * 4; // ff1: 4096x3072 each

  embed_kernel<<<MROWS, 256, 0, stream>>>(tokens, emb, xhi, xlo);

  const dim3 g768(DMODEL / 64, MROWS / 64);   // (12,64)
  const dim3 gff(DFF / 64, MROWS / 64);       // (48,64)
  const dim3 gattn(NSEQ / 64, NHEAD, NB);     // (16,12,4)
  const int splitblocks = (int)(WTOT / 1024); // 6912

  for (int l = 0; l < NDEPTH; ++l) {
    wsplit_kernel<<<splitblocks, 256, 0, stream>>>(
        wq  + (size_t)l * DMODEL * DMODEL,
        wk  + (size_t)l * DMODEL * DMODEL,
        wv  + (size_t)l * DMODEL * DMODEL,
        wo  + (size_t)l * DMODEL * DMODEL,
        wi  + (size_t)l * DFF * DMODEL,
        wof + (size_t)l * DMODEL * DFF,
        whi, wlo);

    // q/k/v projections (q pre-scaled by DH^-0.5)
    gemm_bt<0, 0><<<g768, 256, 0, stream>>>(xhi, xlo, whi + WQ_OFF, wlo + WQ_OFF,
                                            qhi, qlo, nullptr, nullptr,
                                            MROWS, DMODEL, DMODEL, 0.125f);
    gemm_bt<0, 0><<<g768, 256, 0, stream>>>(xhi, xlo, whi + WK_OFF, wlo + WK_OFF,
                                            khi, klo, nullptr, nullptr,
                                            MROWS, DMODEL, DMODEL, 1.f);
    gemm_bt<0, 0><<<g768, 256, 0, stream>>>(xhi, xlo, whi + WV_OFF, wlo + WV_OFF,
                                            vhi, vlo, nullptr, nullptr,
                                            MROWS, DMODEL, DMODEL, 1.f);
    // attention (MFMA flash)
    attn_kernel<<<gattn, 256, 0, stream>>>(qhi, qlo, khi, klo, vhi, vlo, ohi, olo);
    // x = x + attn_out @ wo^T
    gemm_bt<0, 1><<<g768, 256, 0, stream>>>(ohi, olo, whi + WO_OFF, wlo + WO_OFF,
                                            xhi, xlo, xhi, xlo,
                                            MROWS, DMODEL, DMODEL, 1.f);
    // ff1 = relu(x @ wi^T)
    gemm_bt<1, 0><<<gff, 256, 0, stream>>>(xhi, xlo, whi + WI_OFF, wlo + WI_OFF,
                                           fhi, flo, nullptr, nullptr,
                                           MROWS, DFF, DMODEL, 1.f);
    // x = x + ff1 @ wof^T
    gemm_bt<0, 1><<<g768, 256, 0, stream>>>(fhi, flo, whi + WOF_OFF, wlo + WOF_OFF,
                                            xhi, xlo, xhi, xlo,
                                            MROWS, DMODEL, DFF, 1.f);
  }

  ln_kernel<<<MROWS, 256, 0, stream>>>(xhi, xlo, lnw, (float*)d_out);
}

// Round 2
// 2509.850 us; speedup vs baseline: 1.7184x; 1.1074x over previous
//
#include <hip/hip_runtime.h>
#include <cstdint>

#define NB 4
#define NSEQ 1024
#define DMODEL 768
#define NHEAD 12
#define DHEAD 64
#define NDEPTH 6
#define DFF 3072
#define MROWS (NB * NSEQ)   // 4096
#define QKVLD 2304          // fused q|k|v row stride

// weight block element offsets (concatenated wq|wk|wv|wo|wi|wof per layer)
#define WQ_OFF 0L
#define WK_OFF 589824L
#define WV_OFF 1179648L
#define WO_OFF 1769472L
#define WI_OFF 2359296L
#define WOF_OFF 4718592L
#define WTOT 7077888L

typedef __attribute__((ext_vector_type(8))) short short8;
typedef __attribute__((ext_vector_type(4))) float floatx4;

static __device__ __forceinline__ float b2f(unsigned short u) {
  union { unsigned int i; float f; } v; v.i = ((unsigned int)u) << 16; return v.f;
}
static __device__ __forceinline__ unsigned short f2b(float f) {
  union { float f; unsigned int i; } v; v.f = f;
  unsigned int x = v.i;
  return (unsigned short)((x + 0x7fffu + ((x >> 16) & 1u)) >> 16);  // RNE
}
// split f32 -> (hi, lo) bf16 pair; hi+lo reconstructs to ~2^-17 rel
static __device__ __forceinline__ void fsplit(float f, unsigned short& h, unsigned short& l) {
  h = f2b(f);
  l = f2b(f - b2f(h));
}

// async global->LDS, 16B per lane. Dest must be linear: wave-uniform base + lane*16.
static __device__ __forceinline__ void gload16(const unsigned short* g, unsigned short* l) {
  __builtin_amdgcn_global_load_lds(
      (const __attribute__((address_space(1))) void*)g,
      (__attribute__((address_space(3))) void*)l, 16, 0, 0);
}

// ---------------- per-layer weight split f32 -> hi/lo bf16
__global__ __launch_bounds__(256) void wsplit_kernel(
    const float* __restrict__ wq, const float* __restrict__ wk,
    const float* __restrict__ wv, const float* __restrict__ wo,
    const float* __restrict__ wi, const float* __restrict__ wof,
    unsigned short* __restrict__ dhi, unsigned short* __restrict__ dlo)
{
  long i = ((long)blockIdx.x * 256 + threadIdx.x) * 4;
  if (i >= WTOT) return;
  const float* src; long off;
  if (i < WK_OFF)       { src = wq;  off = i - WQ_OFF; }
  else if (i < WV_OFF)  { src = wk;  off = i - WK_OFF; }
  else if (i < WO_OFF)  { src = wv;  off = i - WV_OFF; }
  else if (i < WI_OFF)  { src = wo;  off = i - WO_OFF; }
  else if (i < WOF_OFF) { src = wi;  off = i - WI_OFF; }
  else                  { src = wof; off = i - WOF_OFF; }
  float4 f = *(const float4*)(src + off);
  ushort4 h, l;
  fsplit(f.x, h.x, l.x); fsplit(f.y, h.y, l.y);
  fsplit(f.z, h.z, l.z); fsplit(f.w, h.w, l.w);
  *(ushort4*)(dhi + i) = h;
  *(ushort4*)(dlo + i) = l;
}

// ---------------- embedding gather -> split x
__global__ void embed_kernel(const int* __restrict__ tok,
                             const float* __restrict__ emb,
                             unsigned short* __restrict__ xhi,
                             unsigned short* __restrict__ xlo) {
  const int row = blockIdx.x;
  const int t = tok[row];
  const float* src = emb + (long)t * DMODEL;
  for (int d = threadIdx.x; d < DMODEL; d += 256) {
    unsigned short h, l;
    fsplit(src[d], h, l);
    xhi[(long)row * DMODEL + d] = h;
    xlo[(long)row * DMODEL + d] = l;
  }
}

// ---------------- GEMM: C(MxN) = act(alpha * A(MxK) @ W(NxK)^T [+ resid])
// Split hi/lo bf16, 3-term MFMA (Ah*Wh + Al*Wh + Ah*Wl).
// BM x 128 block tile, linear LDS tiles staged via global_load_lds(16B),
// single-buffered 2-barrier K-loop (m97 structure).
// Wave grid WGM x WGN (WGM*WGN=4); per-wave MT x NT tiles of 16x16.
// QSCALE: columns < DMODEL get alpha (fused-qkv q scaling), others 1.
template<int BM, int WGM, int WGN, int MT, int NT, int RELU, int RESID, int QSCALE>
__global__ __launch_bounds__(256) void gemm128(
    const unsigned short* __restrict__ Ahi, const unsigned short* __restrict__ Alo,
    const unsigned short* __restrict__ Whi, const unsigned short* __restrict__ Wlo,
    unsigned short* __restrict__ Chi, unsigned short* __restrict__ Clo,
    const unsigned short* __restrict__ Rhi, const unsigned short* __restrict__ Rlo,
    int N, int K, float alpha)
{
  __shared__ unsigned short sAh[BM * 32];
  __shared__ unsigned short sAl[BM * 32];
  __shared__ unsigned short sBh[128 * 32];
  __shared__ unsigned short sBl[128 * 32];

  const int tid = threadIdx.x;
  const int bn = blockIdx.x, bm = blockIdx.y;
  const int wave = tid >> 6, lane = tid & 63;
  const int wm = wave / WGN, wn = wave % WGN;
  const int l16 = lane & 15, q4 = lane >> 4;

  // staging: call c covers LDS elems [c*2048, (c+1)*2048); thread -> 8 ushorts
  const int srow = tid >> 2;          // 0..63 row within 64-row stripe
  const int scol = (tid & 3) << 3;    // 0,8,16,24
  const int soff = tid * 8;           // LDS ushort offset within stripe

  floatx4 acc[MT][NT];
  #pragma unroll
  for (int i = 0; i < MT; ++i)
    #pragma unroll
    for (int j = 0; j < NT; ++j) {
      floatx4 z = {0.f, 0.f, 0.f, 0.f};
      acc[i][j] = z;
    }

  const long aB = ((long)bm * BM + srow) * K + scol;
  const long bB = ((long)bn * 128 + srow) * K + scol;

  for (int k0 = 0; k0 < K; k0 += 32) {
    #pragma unroll
    for (int c = 0; c < BM / 64; ++c) {
      gload16(Ahi + aB + (long)c * 64 * K + k0, sAh + c * 2048 + soff);
      gload16(Alo + aB + (long)c * 64 * K + k0, sAl + c * 2048 + soff);
    }
    #pragma unroll
    for (int c = 0; c < 2; ++c) {
      gload16(Whi + bB + (long)c * 64 * K + k0, sBh + c * 2048 + soff);
      gload16(Wlo + bB + (long)c * 64 * K + k0, sBl + c * 2048 + soff);
    }
    __syncthreads();   // compiler drains vmcnt before s_barrier

    short8 ah[MT], al[MT], bh[NT], bl[NT];
    #pragma unroll
    for (int mt = 0; mt < MT; ++mt) {
      const int row = wm * (MT * 16) + mt * 16 + l16;
      ah[mt] = *(const short8*)&sAh[row * 32 + q4 * 8];
      al[mt] = *(const short8*)&sAl[row * 32 + q4 * 8];
    }
    #pragma unroll
    for (int nt = 0; nt < NT; ++nt) {
      const int row = wn * (NT * 16) + nt * 16 + l16;
      bh[nt] = *(const short8*)&sBh[row * 32 + q4 * 8];
      bl[nt] = *(const short8*)&sBl[row * 32 + q4 * 8];
    }

    #pragma unroll
    for (int mt = 0; mt < MT; ++mt)
      #pragma unroll
      for (int nt = 0; nt < NT; ++nt)
        acc[mt][nt] = __builtin_amdgcn_mfma_f32_16x16x32_bf16(ah[mt], bh[nt], acc[mt][nt], 0, 0, 0);
    #pragma unroll
    for (int mt = 0; mt < MT; ++mt)
      #pragma unroll
      for (int nt = 0; nt < NT; ++nt)
        acc[mt][nt] = __builtin_amdgcn_mfma_f32_16x16x32_bf16(al[mt], bh[nt], acc[mt][nt], 0, 0, 0);
    #pragma unroll
    for (int mt = 0; mt < MT; ++mt)
      #pragma unroll
      for (int nt = 0; nt < NT; ++nt)
        acc[mt][nt] = __builtin_amdgcn_mfma_f32_16x16x32_bf16(ah[mt], bl[nt], acc[mt][nt], 0, 0, 0);
    __syncthreads();
  }

  // epilogue: C/D layout col=lane&15, row=(lane>>4)*4+reg
  #pragma unroll
  for (int mt = 0; mt < MT; ++mt) {
    const int r0 = bm * BM + wm * (MT * 16) + mt * 16 + q4 * 4;
    #pragma unroll
    for (int nt = 0; nt < NT; ++nt) {
      const int c = bn * 128 + wn * (NT * 16) + nt * 16 + l16;
      float sc = alpha;
      if (QSCALE) sc = (c < DMODEL) ? alpha : 1.f;
      #pragma unroll
      for (int r = 0; r < 4; ++r) {
        float vv = acc[mt][nt][r] * sc;
        const long idx = (long)(r0 + r) * N + c;
        if (RESID) vv += b2f(Rhi[idx]) + b2f(Rlo[idx]);
        if (RELU)  vv = fmaxf(vv, 0.f);
        unsigned short h, l;
        fsplit(vv, h, l);
        Chi[idx] = h; Clo[idx] = l;
      }
    }
  }
}

// ---------------- flash attention, MFMA path (mask all-ones -> ignored).
// Q/K/V read from the fused qkv buffer (row stride QKVLD, col offsets 0/768/1536).
// Block = 64 query rows of one (b,h); 4 waves, each wave owns 16 rows.
__global__ __launch_bounds__(256) void attn_kernel(
    const unsigned short* __restrict__ qkvhi, const unsigned short* __restrict__ qkvlo,
    unsigned short* __restrict__ ohi, unsigned short* __restrict__ olo)
{
  __shared__ unsigned short ks_h[64][72];
  __shared__ unsigned short ks_l[64][72];
  __shared__ unsigned short vt_h[64][72];
  __shared__ unsigned short vt_l[64][72];
  __shared__ unsigned short ps_h[64][72];
  __shared__ unsigned short ps_l[64][72];

  const int tid = threadIdx.x;
  const int iq = blockIdx.x, h = blockIdx.y, b = blockIdx.z;
  const int wave = tid >> 6, lane = tid & 63;
  const int l16 = lane & 15, g4 = lane >> 4;
  const long qb = ((long)b * NSEQ) * QKVLD + h * DHEAD;
  const long kb = qb + DMODEL;
  const long vb = qb + 2 * DMODEL;
  const long ob = ((long)b * NSEQ) * DMODEL + h * DHEAD;
  const int q0 = iq * 64;

  // Q fragments straight from global (A-frag layout is contiguous in memory)
  short8 qh[2], ql[2];
  {
    const long qr = qb + (long)(q0 + wave * 16 + l16) * QKVLD + g4 * 8;
    qh[0] = *(const short8*)(qkvhi + qr);
    qh[1] = *(const short8*)(qkvhi + qr + 32);
    ql[0] = *(const short8*)(qkvlo + qr);
    ql[1] = *(const short8*)(qkvlo + qr + 32);
  }

  floatx4 oacc[4];
  #pragma unroll
  for (int nt = 0; nt < 4; ++nt) { floatx4 z = {0.f,0.f,0.f,0.f}; oacc[nt] = z; }
  float mrow[4] = {-INFINITY, -INFINITY, -INFINITY, -INFINITY};
  float lrow[4] = {0.f, 0.f, 0.f, 0.f};

  const int skey = tid >> 3;          // 0..31 staging key
  const int sd0  = (tid & 7) * 8;     // 0..56 staging dh offset

  for (int jc = 0; jc < NSEQ / 64; ++jc) {
    const int j0 = jc * 64;
    if (jc) __syncthreads();

    #pragma unroll
    for (int half = 0; half < 2; ++half) {
      const int key = skey + half * 32;
      const long offk = kb + (long)(j0 + key) * QKVLD + sd0;
      const long offv = vb + (long)(j0 + key) * QKVLD + sd0;
      short8 kh8 = *(const short8*)(qkvhi + offk);
      short8 kl8 = *(const short8*)(qkvlo + offk);
      short8 vh8 = *(const short8*)(qkvhi + offv);
      short8 vl8 = *(const short8*)(qkvlo + offv);
      *(short8*)&ks_h[key][sd0] = kh8;
      *(short8*)&ks_l[key][sd0] = kl8;
      #pragma unroll
      for (int u = 0; u < 8; ++u) {
        const int dh = sd0 + u;
        const int cc = key ^ ((dh >> 3) << 3);
        vt_h[dh][cc] = (unsigned short)vh8[u];
        vt_l[dh][cc] = (unsigned short)vl8[u];
      }
    }
    __syncthreads();

    // ---- S = Q @ K^T
    floatx4 sacc[4];
    #pragma unroll
    for (int nt = 0; nt < 4; ++nt) { floatx4 z = {0.f,0.f,0.f,0.f}; sacc[nt] = z; }
    #pragma unroll
    for (int nt = 0; nt < 4; ++nt) {
      #pragma unroll
      for (int ks = 0; ks < 2; ++ks) {
        short8 kh8 = *(const short8*)&ks_h[nt * 16 + l16][ks * 32 + g4 * 8];
        short8 kl8 = *(const short8*)&ks_l[nt * 16 + l16][ks * 32 + g4 * 8];
        sacc[nt] = __builtin_amdgcn_mfma_f32_16x16x32_bf16(qh[ks], kh8, sacc[nt], 0, 0, 0);
        sacc[nt] = __builtin_amdgcn_mfma_f32_16x16x32_bf16(ql[ks], kh8, sacc[nt], 0, 0, 0);
        sacc[nt] = __builtin_amdgcn_mfma_f32_16x16x32_bf16(qh[ks], kl8, sacc[nt], 0, 0, 0);
      }
    }

    // ---- online softmax; row r lives on the 16 lanes sharing g4
    float mx[4], al[4];
    #pragma unroll
    for (int r = 0; r < 4; ++r) {
      float m0 = fmaxf(fmaxf(sacc[0][r], sacc[1][r]), fmaxf(sacc[2][r], sacc[3][r]));
      m0 = fmaxf(m0, __shfl_xor(m0, 1));
      m0 = fmaxf(m0, __shfl_xor(m0, 2));
      m0 = fmaxf(m0, __shfl_xor(m0, 4));
      m0 = fmaxf(m0, __shfl_xor(m0, 8));
      const float mn = fmaxf(mrow[r], m0);
      al[r] = __expf(mrow[r] - mn);
      mrow[r] = mn;
      mx[r] = mn;
    }
    #pragma unroll
    for (int r = 0; r < 4; ++r) {
      const int qrow = wave * 16 + g4 * 4 + r;
      float rs = 0.f;
      #pragma unroll
      for (int nt = 0; nt < 4; ++nt) {
        const float p = __expf(sacc[nt][r] - mx[r]);
        rs += p;
        unsigned short ph, pl;
        fsplit(p, ph, pl);
        ps_h[qrow][nt * 16 + l16] = ph;
        ps_l[qrow][nt * 16 + l16] = pl;
      }
      rs += __shfl_xor(rs, 1);
      rs += __shfl_xor(rs, 2);
      rs += __shfl_xor(rs, 4);
      rs += __shfl_xor(rs, 8);
      lrow[r] = lrow[r] * al[r] + rs;
      oacc[0][r] *= al[r]; oacc[1][r] *= al[r];
      oacc[2][r] *= al[r]; oacc[3][r] *= al[r];
    }
    __syncthreads();

    // ---- O += P @ V
    #pragma unroll
    for (int ks = 0; ks < 2; ++ks) {
      short8 ph8 = *(const short8*)&ps_h[wave * 16 + l16][ks * 32 + g4 * 8];
      short8 pl8 = *(const short8*)&ps_l[wave * 16 + l16][ks * 32 + g4 * 8];
      #pragma unroll
      for (int nt = 0; nt < 4; ++nt) {
        const int dh = nt * 16 + l16;
        const int cb = (ks * 32 + g4 * 8) ^ ((dh >> 3) << 3);
        short8 vh8 = *(const short8*)&vt_h[dh][cb];
        short8 vl8 = *(const short8*)&vt_l[dh][cb];
        oacc[nt] = __builtin_amdgcn_mfma_f32_16x16x32_bf16(ph8, vh8, oacc[nt], 0, 0, 0);
        oacc[nt] = __builtin_amdgcn_mfma_f32_16x16x32_bf16(pl8, vh8, oacc[nt], 0, 0, 0);
        oacc[nt] = __builtin_amdgcn_mfma_f32_16x16x32_bf16(ph8, vl8, oacc[nt], 0, 0, 0);
      }
    }
  }

  // ---- epilogue: O / l, split-store
  const long orbase = ob + (long)(q0 + wave * 16 + g4 * 4) * DMODEL;
  #pragma unroll
  for (int r = 0; r < 4; ++r) {
    const float inv = 1.f / lrow[r];
    #pragma unroll
    for (int nt = 0; nt < 4; ++nt) {
      unsigned short hh, ll;
      fsplit(oacc[nt][r] * inv, hh, ll);
      const long idx = orbase + (long)r * DMODEL + nt * 16 + l16;
      ohi[idx] = hh; olo[idx] = ll;
    }
  }
}

// ---------------- final T5 RMS layernorm, split in -> f32 out
__global__ __launch_bounds__(256) void ln_kernel(const unsigned short* __restrict__ xhi,
                                                 const unsigned short* __restrict__ xlo,
                                                 const float* __restrict__ w,
                                                 float* __restrict__ out)
{
  __shared__ float red[256];
  const int row = blockIdx.x;
  const long rb = (long)row * DMODEL;
  float ss = 0.f;
  for (int d = threadIdx.x; d < DMODEL; d += 256) {
    float v = b2f(xhi[rb + d]) + b2f(xlo[rb + d]);
    ss += v * v;
  }
  red[threadIdx.x] = ss;
  __syncthreads();
  for (int s = 128; s > 0; s >>= 1) {
    if (threadIdx.x < s) red[threadIdx.x] += red[threadIdx.x + s];
    __syncthreads();
  }
  const float rs = rsqrtf(red[0] * (1.f / DMODEL) + 1e-6f);
  for (int d = threadIdx.x; d < DMODEL; d += 256) {
    float v = b2f(xhi[rb + d]) + b2f(xlo[rb + d]);
    out[rb + d] = w[d] * v * rs;
  }
}

extern "C" void kernel_launch(void* const* d_in, const int* in_sizes, int n_in,
                              void* d_out, int out_size, void* d_ws, size_t ws_size,
                              hipStream_t stream)
{
  const int* tokens   = (const int*)d_in[0];
  // d_in[1] = mask (all ones in this problem) — unused
  const float* emb    = (const float*)d_in[2];
  const float* wq     = (const float*)d_in[3];
  const float* wk     = (const float*)d_in[4];
  const float* wv     = (const float*)d_in[5];
  const float* wo     = (const float*)d_in[6];
  const float* wi     = (const float*)d_in[7];
  const float* wof    = (const float*)d_in[8];
  const float* lnw    = (const float*)d_in[9];

  // ws layout:
  //   x_hi,x_lo               2 x AS
  //   act block (8 x AS):     qkv_hi (3AS) | qkv_lo (3AS) | o_hi | o_lo
  //                           (reused in ff phase: f_hi = act[0..4AS), f_lo = act[4AS..8AS))
  //   w_hi,w_lo               2 x WTOT
  const size_t AS = (size_t)MROWS * DMODEL;   // 3,145,728 elems
  char* p = (char*)d_ws;
  unsigned short* xhi = (unsigned short*)p;  p += AS * 2;
  unsigned short* xlo = (unsigned short*)p;  p += AS * 2;
  unsigned short* act = (unsigned short*)p;  p += AS * 2 * 8;
  unsigned short* whi = (unsigned short*)p;  p += (size_t)WTOT * 2;
  unsigned short* wlo = (unsigned short*)p;  p += (size_t)WTOT * 2;

  unsigned short* qkvhi = act + AS * 0;   // 4096 x 2304
  unsigned short* qkvlo = act + AS * 3;
  unsigned short* ohi   = act + AS * 6;
  unsigned short* olo   = act + AS * 7;
  unsigned short* fhi   = act + AS * 0;   // 4096 x 3072 (qkv dead by then)
  unsigned short* flo   = act + AS * 4;   // (o dead by then)

  embed_kernel<<<MROWS, 256, 0, stream>>>(tokens, emb, xhi, xlo);

  const dim3 gqkv(QKVLD / 128, MROWS / 128);  // (18,32)
  const dim3 gwo(DMODEL / 128, MROWS / 64);   // (6,64)
  const dim3 gwi(DFF / 128, MROWS / 128);     // (24,32)
  const dim3 gattn(NSEQ / 64, NHEAD, NB);     // (16,12,4)
  const int splitblocks = (int)(WTOT / 1024); // 6912

  for (int l = 0; l < NDEPTH; ++l) {
    wsplit_kernel<<<splitblocks, 256, 0, stream>>>(
        wq  + (size_t)l * DMODEL * DMODEL,
        wk  + (size_t)l * DMODEL * DMODEL,
        wv  + (size_t)l * DMODEL * DMODEL,
        wo  + (size_t)l * DMODEL * DMODEL,
        wi  + (size_t)l * DFF * DMODEL,
        wof + (size_t)l * DMODEL * DFF,
        whi, wlo);

    // fused qkv projection (q columns pre-scaled by DH^-0.5)
    gemm128<128,2,2,4,4, 0,0,1><<<gqkv, 256, 0, stream>>>(
        xhi, xlo, whi + WQ_OFF, wlo + WQ_OFF,
        qkvhi, qkvlo, nullptr, nullptr, QKVLD, DMODEL, 0.125f);
    // attention (MFMA flash)
    attn_kernel<<<gattn, 256, 0, stream>>>(qkvhi, qkvlo, ohi, olo);
    // x = x + attn_out @ wo^T
    gemm128<64,1,4,4,2, 0,1,0><<<gwo, 256, 0, stream>>>(
        ohi, olo, whi + WO_OFF, wlo + WO_OFF,
        xhi, xlo, xhi, xlo, DMODEL, DMODEL, 1.f);
    // ff1 = relu(x @ wi^T)
    gemm128<128,2,2,4,4, 1,0,0><<<gwi, 256, 0, stream>>>(
        xhi, xlo, whi + WI_OFF, wlo + WI_OFF,
        fhi, flo, nullptr, nullptr, DFF, DMODEL, 1.f);
    // x = x + ff1 @ wof^T
    gemm128<64,1,4,4,2, 0,1,0><<<gwo, 256, 0, stream>>>(
        fhi, flo, whi + WOF_OFF, wlo + WOF_OFF,
        xhi, xlo, xhi, xlo, DMODEL, DFF, 1.f);
  }

  ln_kernel<<<MROWS, 256, 0, stream>>>(xhi, xlo, lnw, (float*)d_out);
}

// Round 4
// 2292.736 us; speedup vs baseline: 1.8812x; 1.0947x over previous
//
#include <hip/hip_runtime.h>
#include <cstdint>

#define NB 4
#define NSEQ 1024
#define DMODEL 768
#define NHEAD 12
#define DHEAD 64
#define NDEPTH 6
#define DFF 3072
#define MROWS (NB * NSEQ)   // 4096
#define QKVLD 2304          // fused q|k|v row stride

// weight block element offsets (concatenated wq|wk|wv|wo|wi|wof per layer)
#define WQ_OFF 0L
#define WK_OFF 589824L
#define WV_OFF 1179648L
#define WO_OFF 1769472L
#define WI_OFF 2359296L
#define WOF_OFF 4718592L
#define WTOT 7077888L

typedef __attribute__((ext_vector_type(8))) short short8;
typedef __attribute__((ext_vector_type(4))) float floatx4;

static __device__ __forceinline__ float b2f(unsigned short u) {
  union { unsigned int i; float f; } v; v.i = ((unsigned int)u) << 16; return v.f;
}
static __device__ __forceinline__ unsigned short f2b(float f) {
  union { float f; unsigned int i; } v; v.f = f;
  unsigned int x = v.i;
  return (unsigned short)((x + 0x7fffu + ((x >> 16) & 1u)) >> 16);  // RNE
}
// split f32 -> (hi, lo) bf16 pair; hi+lo reconstructs to ~2^-17 rel
static __device__ __forceinline__ void fsplit(float f, unsigned short& h, unsigned short& l) {
  h = f2b(f);
  l = f2b(f - b2f(h));
}

// async global->LDS, 16B per lane. Dest must be linear: wave-uniform base + lane*16.
static __device__ __forceinline__ void gload16(const unsigned short* g, unsigned short* l) {
  __builtin_amdgcn_global_load_lds(
      (const __attribute__((address_space(1))) void*)g,
      (__attribute__((address_space(3))) void*)l, 16, 0, 0);
}

// ---------------- per-layer weight split f32 -> hi/lo bf16
__global__ __launch_bounds__(256) void wsplit_kernel(
    const float* __restrict__ wq, const float* __restrict__ wk,
    const float* __restrict__ wv, const float* __restrict__ wo,
    const float* __restrict__ wi, const float* __restrict__ wof,
    unsigned short* __restrict__ dhi, unsigned short* __restrict__ dlo)
{
  long i = ((long)blockIdx.x * 256 + threadIdx.x) * 4;
  if (i >= WTOT) return;
  const float* src; long off;
  if (i < WK_OFF)       { src = wq;  off = i - WQ_OFF; }
  else if (i < WV_OFF)  { src = wk;  off = i - WK_OFF; }
  else if (i < WO_OFF)  { src = wv;  off = i - WV_OFF; }
  else if (i < WI_OFF)  { src = wo;  off = i - WO_OFF; }
  else if (i < WOF_OFF) { src = wi;  off = i - WI_OFF; }
  else                  { src = wof; off = i - WOF_OFF; }
  float4 f = *(const float4*)(src + off);
  ushort4 h, l;
  fsplit(f.x, h.x, l.x); fsplit(f.y, h.y, l.y);
  fsplit(f.z, h.z, l.z); fsplit(f.w, h.w, l.w);
  *(ushort4*)(dhi + i) = h;
  *(ushort4*)(dlo + i) = l;
}

// ---------------- embedding gather -> split x
__global__ void embed_kernel(const int* __restrict__ tok,
                             const float* __restrict__ emb,
                             unsigned short* __restrict__ xhi,
                             unsigned short* __restrict__ xlo) {
  const int row = blockIdx.x;
  const int t = tok[row];
  const float* src = emb + (long)t * DMODEL;
  for (int d = threadIdx.x; d < DMODEL; d += 256) {
    unsigned short h, l;
    fsplit(src[d], h, l);
    xhi[(long)row * DMODEL + d] = h;
    xlo[(long)row * DMODEL + d] = l;
  }
}

// ---------------- GEMM: C(MxN) = act(alpha * A(MxK) @ W(NxK)^T [+ resid])
// Split hi/lo bf16, 3-term MFMA (Ah*Wh + Al*Wh + Ah*Wl).
// BM x 128 block tile, K-step BK (32 or 64), linear LDS via global_load_lds(16B),
// single-buffered 2-barrier K-loop (m97 structure).
// BK=64: rows are 128B -> 16-way bank conflict if linear. Fix per rule #21:
// LDS dest stays linear, global SOURCE col-group is XOR-permuted (col8 ^= row&7),
// fragment reads apply the same XOR -> 2-way (free). BK=32: XM=0 (unchanged).
// Wave grid WGM x WGN (WGM*WGN=4); per-wave MT x NT tiles of 16x16.
// QSCALE: columns < DMODEL get alpha (fused-qkv q scaling), others 1.
template<int BM, int BK, int WGM, int WGN, int MT, int NT, int RELU, int RESID, int QSCALE>
__global__ __launch_bounds__(256) void gemm128(
    const unsigned short* __restrict__ Ahi, const unsigned short* __restrict__ Alo,
    const unsigned short* __restrict__ Whi, const unsigned short* __restrict__ Wlo,
    unsigned short* __restrict__ Chi, unsigned short* __restrict__ Clo,
    const unsigned short* __restrict__ Rhi, const unsigned short* __restrict__ Rlo,
    int N, int K, float alpha)
{
  __shared__ unsigned short sAh[BM * BK];
  __shared__ unsigned short sAl[BM * BK];
  __shared__ unsigned short sBh[128 * BK];
  __shared__ unsigned short sBl[128 * BK];

  constexpr int XM = (BK == 64) ? 7 : 0;   // swizzle mask (col-groups of 8)

  const int tid = threadIdx.x;
  const int bn = blockIdx.x, bm = blockIdx.y;
  const int wave = tid >> 6, lane = tid & 63;
  const int wm = wave / WGN, wn = wave % WGN;
  const int l16 = lane & 15, q4 = lane >> 4;

  // staging: gload chunk c covers LDS elems [c*2048, (c+1)*2048)
  constexpr int RPC = 2048 / BK;              // rows per chunk
  const int srow = tid / (BK / 8);            // row within chunk
  const int scol = (((tid % (BK / 8)) ^ (srow & XM))) * 8;  // swizzled src col
  const int soff = tid * 8;                   // linear ushort offset within chunk

  floatx4 acc[MT][NT];
  #pragma unroll
  for (int i = 0; i < MT; ++i)
    #pragma unroll
    for (int j = 0; j < NT; ++j) {
      floatx4 z = {0.f, 0.f, 0.f, 0.f};
      acc[i][j] = z;
    }

  const long aB = ((long)bm * BM + srow) * K + scol;
  const long bB = ((long)bn * 128 + srow) * K + scol;

  for (int k0 = 0; k0 < K; k0 += BK) {
    #pragma unroll
    for (int c = 0; c < (BM * BK) / 2048; ++c) {
      gload16(Ahi + aB + (long)c * RPC * K + k0, sAh + c * 2048 + soff);
      gload16(Alo + aB + (long)c * RPC * K + k0, sAl + c * 2048 + soff);
    }
    #pragma unroll
    for (int c = 0; c < (128 * BK) / 2048; ++c) {
      gload16(Whi + bB + (long)c * RPC * K + k0, sBh + c * 2048 + soff);
      gload16(Wlo + bB + (long)c * RPC * K + k0, sBl + c * 2048 + soff);
    }
    __syncthreads();   // compiler drains vmcnt before s_barrier

    #pragma unroll
    for (int kk = 0; kk < BK / 32; ++kk) {
      short8 ah[MT], am[MT], bh[NT], bl[NT];
      #pragma unroll
      for (int mt = 0; mt < MT; ++mt) {
        const int row = wm * (MT * 16) + mt * 16 + l16;
        const int cg  = ((kk * 4 + q4) ^ (row & XM)) * 8;
        ah[mt] = *(const short8*)&sAh[row * BK + cg];
        am[mt] = *(const short8*)&sAl[row * BK + cg];
      }
      #pragma unroll
      for (int nt = 0; nt < NT; ++nt) {
        const int row = wn * (NT * 16) + nt * 16 + l16;
        const int cg  = ((kk * 4 + q4) ^ (row & XM)) * 8;
        bh[nt] = *(const short8*)&sBh[row * BK + cg];
        bl[nt] = *(const short8*)&sBl[row * BK + cg];
      }

      #pragma unroll
      for (int mt = 0; mt < MT; ++mt)
        #pragma unroll
        for (int nt = 0; nt < NT; ++nt)
          acc[mt][nt] = __builtin_amdgcn_mfma_f32_16x16x32_bf16(ah[mt], bh[nt], acc[mt][nt], 0, 0, 0);
      #pragma unroll
      for (int mt = 0; mt < MT; ++mt)
        #pragma unroll
        for (int nt = 0; nt < NT; ++nt)
          acc[mt][nt] = __builtin_amdgcn_mfma_f32_16x16x32_bf16(am[mt], bh[nt], acc[mt][nt], 0, 0, 0);
      #pragma unroll
      for (int mt = 0; mt < MT; ++mt)
        #pragma unroll
        for (int nt = 0; nt < NT; ++nt)
          acc[mt][nt] = __builtin_amdgcn_mfma_f32_16x16x32_bf16(ah[mt], bl[nt], acc[mt][nt], 0, 0, 0);
    }
    __syncthreads();
  }

  // epilogue: C/D layout col=lane&15, row=(lane>>4)*4+reg
  #pragma unroll
  for (int mt = 0; mt < MT; ++mt) {
    const int r0 = bm * BM + wm * (MT * 16) + mt * 16 + q4 * 4;
    #pragma unroll
    for (int nt = 0; nt < NT; ++nt) {
      const int c = bn * 128 + wn * (NT * 16) + nt * 16 + l16;
      float sc = alpha;
      if (QSCALE) sc = (c < DMODEL) ? alpha : 1.f;
      #pragma unroll
      for (int r = 0; r < 4; ++r) {
        float vv = acc[mt][nt][r] * sc;
        const long idx = (long)(r0 + r) * N + c;
        if (RESID) vv += b2f(Rhi[idx]) + b2f(Rlo[idx]);
        if (RELU)  vv = fmaxf(vv, 0.f);
        unsigned short h, l;
        fsplit(vv, h, l);
        Chi[idx] = h; Clo[idx] = l;
      }
    }
  }
}

// ---------------- flash attention, MFMA path (mask all-ones -> ignored).
// Q/K/V read from the fused qkv buffer (row stride QKVLD, col offsets 0/768/1536).
// Block = 64 query rows of one (b,h); 4 waves, each wave owns 16 rows.
// LDS: K and P time-share kp_h/kp_l (K dead after QK^T) -> 36.9 KB, 4 blocks/CU.
__global__ __launch_bounds__(256) void attn_kernel(
    const unsigned short* __restrict__ qkvhi, const unsigned short* __restrict__ qkvlo,
    unsigned short* __restrict__ ohi, unsigned short* __restrict__ olo)
{
  __shared__ unsigned short kp_h[64][72];   // K, then P
  __shared__ unsigned short kp_l[64][72];
  __shared__ unsigned short vt_h[64][72];   // V transposed (XOR-8 swizzle)
  __shared__ unsigned short vt_l[64][72];

  const int tid = threadIdx.x;
  const int iq = blockIdx.x, h = blockIdx.y, b = blockIdx.z;
  const int wave = tid >> 6, lane = tid & 63;
  const int l16 = lane & 15, g4 = lane >> 4;
  const long qb = ((long)b * NSEQ) * QKVLD + h * DHEAD;
  const long kb = qb + DMODEL;
  const long vb = qb + 2 * DMODEL;
  const long ob = ((long)b * NSEQ) * DMODEL + h * DHEAD;
  const int q0 = iq * 64;

  // Q fragments straight from global (A-frag layout is contiguous in memory)
  short8 qh[2], ql[2];
  {
    const long qr = qb + (long)(q0 + wave * 16 + l16) * QKVLD + g4 * 8;
    qh[0] = *(const short8*)(qkvhi + qr);
    qh[1] = *(const short8*)(qkvhi + qr + 32);
    ql[0] = *(const short8*)(qkvlo + qr);
    ql[1] = *(const short8*)(qkvlo + qr + 32);
  }

  floatx4 oacc[4];
  #pragma unroll
  for (int nt = 0; nt < 4; ++nt) { floatx4 z = {0.f,0.f,0.f,0.f}; oacc[nt] = z; }
  float mrow[4] = {-INFINITY, -INFINITY, -INFINITY, -INFINITY};
  float lrow[4] = {0.f, 0.f, 0.f, 0.f};

  const int skey = tid >> 3;          // 0..31 staging key
  const int sd0  = (tid & 7) * 8;     // 0..56 staging dh offset

  for (int jc = 0; jc < NSEQ / 64; ++jc) {
    const int j0 = jc * 64;
    if (jc) __syncthreads();   // prev chunk's P/V reads done before overwrite

    #pragma unroll
    for (int half = 0; half < 2; ++half) {
      const int key = skey + half * 32;
      const long offk = kb + (long)(j0 + key) * QKVLD + sd0;
      const long offv = vb + (long)(j0 + key) * QKVLD + sd0;
      short8 kh8 = *(const short8*)(qkvhi + offk);
      short8 kl8 = *(const short8*)(qkvlo + offk);
      short8 vh8 = *(const short8*)(qkvhi + offv);
      short8 vl8 = *(const short8*)(qkvlo + offv);
      *(short8*)&kp_h[key][sd0] = kh8;
      *(short8*)&kp_l[key][sd0] = kl8;
      #pragma unroll
      for (int u = 0; u < 8; ++u) {
        const int dh = sd0 + u;
        const int cc = key ^ ((dh >> 3) << 3);
        vt_h[dh][cc] = (unsigned short)vh8[u];
        vt_l[dh][cc] = (unsigned short)vl8[u];
      }
    }
    __syncthreads();

    // ---- S = Q @ K^T
    floatx4 sacc[4];
    #pragma unroll
    for (int nt = 0; nt < 4; ++nt) { floatx4 z = {0.f,0.f,0.f,0.f}; sacc[nt] = z; }
    #pragma unroll
    for (int nt = 0; nt < 4; ++nt) {
      #pragma unroll
      for (int ks = 0; ks < 2; ++ks) {
        short8 kh8 = *(const short8*)&kp_h[nt * 16 + l16][ks * 32 + g4 * 8];
        short8 kl8 = *(const short8*)&kp_l[nt * 16 + l16][ks * 32 + g4 * 8];
        sacc[nt] = __builtin_amdgcn_mfma_f32_16x16x32_bf16(qh[ks], kh8, sacc[nt], 0, 0, 0);
        sacc[nt] = __builtin_amdgcn_mfma_f32_16x16x32_bf16(ql[ks], kh8, sacc[nt], 0, 0, 0);
        sacc[nt] = __builtin_amdgcn_mfma_f32_16x16x32_bf16(qh[ks], kl8, sacc[nt], 0, 0, 0);
      }
    }
    __syncthreads();   // K reads drained; kp_* may now hold P

    // ---- online softmax; row r lives on the 16 lanes sharing g4
    float mx[4], al[4];
    #pragma unroll
    for (int r = 0; r < 4; ++r) {
      float m0 = fmaxf(fmaxf(sacc[0][r], sacc[1][r]), fmaxf(sacc[2][r], sacc[3][r]));
      m0 = fmaxf(m0, __shfl_xor(m0, 1));
      m0 = fmaxf(m0, __shfl_xor(m0, 2));
      m0 = fmaxf(m0, __shfl_xor(m0, 4));
      m0 = fmaxf(m0, __shfl_xor(m0, 8));
      const float mn = fmaxf(mrow[r], m0);
      al[r] = __expf(mrow[r] - mn);
      mrow[r] = mn;
      mx[r] = mn;
    }
    #pragma unroll
    for (int r = 0; r < 4; ++r) {
      const int qrow = wave * 16 + g4 * 4 + r;
      float rs = 0.f;
      #pragma unroll
      for (int nt = 0; nt < 4; ++nt) {
        const float p = __expf(sacc[nt][r] - mx[r]);
        rs += p;
        unsigned short ph, pl;
        fsplit(p, ph, pl);
        kp_h[qrow][nt * 16 + l16] = ph;
        kp_l[qrow][nt * 16 + l16] = pl;
      }
      rs += __shfl_xor(rs, 1);
      rs += __shfl_xor(rs, 2);
      rs += __shfl_xor(rs, 4);
      rs += __shfl_xor(rs, 8);
      lrow[r] = lrow[r] * al[r] + rs;
      oacc[0][r] *= al[r]; oacc[1][r] *= al[r];
      oacc[2][r] *= al[r]; oacc[3][r] *= al[r];
    }
    __syncthreads();   // P visible

    // ---- O += P @ V
    #pragma unroll
    for (int ks = 0; ks < 2; ++ks) {
      short8 ph8 = *(const short8*)&kp_h[wave * 16 + l16][ks * 32 + g4 * 8];
      short8 pl8 = *(const short8*)&kp_l[wave * 16 + l16][ks * 32 + g4 * 8];
      #pragma unroll
      for (int nt = 0; nt < 4; ++nt) {
        const int dh = nt * 16 + l16;
        const int cb = (ks * 32 + g4 * 8) ^ ((dh >> 3) << 3);
        short8 vh8 = *(const short8*)&vt_h[dh][cb];
        short8 vl8 = *(const short8*)&vt_l[dh][cb];
        oacc[nt] = __builtin_amdgcn_mfma_f32_16x16x32_bf16(ph8, vh8, oacc[nt], 0, 0, 0);
        oacc[nt] = __builtin_amdgcn_mfma_f32_16x16x32_bf16(pl8, vh8, oacc[nt], 0, 0, 0);
        oacc[nt] = __builtin_amdgcn_mfma_f32_16x16x32_bf16(ph8, vl8, oacc[nt], 0, 0, 0);
      }
    }
  }

  // ---- epilogue: O / l, split-store
  const long orbase = ob + (long)(q0 + wave * 16 + g4 * 4) * DMODEL;
  #pragma unroll
  for (int r = 0; r < 4; ++r) {
    const float inv = 1.f / lrow[r];
    #pragma unroll
    for (int nt = 0; nt < 4; ++nt) {
      unsigned short hh, ll;
      fsplit(oacc[nt][r] * inv, hh, ll);
      const long idx = orbase + (long)r * DMODEL + nt * 16 + l16;
      ohi[idx] = hh; olo[idx] = ll;
    }
  }
}

// ---------------- final T5 RMS layernorm, split in -> f32 out
__global__ __launch_bounds__(256) void ln_kernel(const unsigned short* __restrict__ xhi,
                                                 const unsigned short* __restrict__ xlo,
                                                 const float* __restrict__ w,
                                                 float* __restrict__ out)
{
  __shared__ float red[256];
  const int row = blockIdx.x;
  const long rb = (long)row * DMODEL;
  float ss = 0.f;
  for (int d = threadIdx.x; d < DMODEL; d += 256) {
    float v = b2f(xhi[rb + d]) + b2f(xlo[rb + d]);
    ss += v * v;
  }
  red[threadIdx.x] = ss;
  __syncthreads();
  for (int s = 128; s > 0; s >>= 1) {
    if (threadIdx.x < s) red[threadIdx.x] += red[threadIdx.x + s];
    __syncthreads();
  }
  const float rs = rsqrtf(red[0] * (1.f / DMODEL) + 1e-6f);
  for (int d = threadIdx.x; d < DMODEL; d += 256) {
    float v = b2f(xhi[rb + d]) + b2f(xlo[rb + d]);
    out[rb + d] = w[d] * v * rs;
  }
}

extern "C" void kernel_launch(void* const* d_in, const int* in_sizes, int n_in,
                              void* d_out, int out_size, void* d_ws, size_t ws_size,
                              hipStream_t stream)
{
  const int* tokens   = (const int*)d_in[0];
  // d_in[1] = mask (all ones in this problem) — unused
  const float* emb    = (const float*)d_in[2];
  const float* wq     = (const float*)d_in[3];
  const float* wk     = (const float*)d_in[4];
  const float* wv     = (const float*)d_in[5];
  const float* wo     = (const float*)d_in[6];
  const float* wi     = (const float*)d_in[7];
  const float* wof    = (const float*)d_in[8];
  const float* lnw    = (const float*)d_in[9];

  const size_t AS = (size_t)MROWS * DMODEL;   // 3,145,728 elems
  char* p = (char*)d_ws;
  unsigned short* xhi = (unsigned short*)p;  p += AS * 2;
  unsigned short* xlo = (unsigned short*)p;  p += AS * 2;
  unsigned short* act = (unsigned short*)p;  p += AS * 2 * 8;
  unsigned short* whi = (unsigned short*)p;  p += (size_t)WTOT * 2;
  unsigned short* wlo = (unsigned short*)p;  p += (size_t)WTOT * 2;

  unsigned short* qkvhi = act + AS * 0;   // 4096 x 2304
  unsigned short* qkvlo = act + AS * 3;
  unsigned short* ohi   = act + AS * 6;
  unsigned short* olo   = act + AS * 7;
  unsigned short* fhi   = act + AS * 0;   // 4096 x 3072 (qkv dead by then)
  unsigned short* flo   = act + AS * 4;   // (o dead by then)

  embed_kernel<<<MROWS, 256, 0, stream>>>(tokens, emb, xhi, xlo);

  const dim3 gqkv(QKVLD / 128, MROWS / 128);  // (18,32)
  const dim3 gwo(DMODEL / 128, MROWS / 64);   // (6,64)
  const dim3 gwi(DFF / 128, MROWS / 128);     // (24,32)
  const dim3 gattn(NSEQ / 64, NHEAD, NB);     // (16,12,4)
  const int splitblocks = (int)(WTOT / 1024); // 6912

  for (int l = 0; l < NDEPTH; ++l) {
    wsplit_kernel<<<splitblocks, 256, 0, stream>>>(
        wq  + (size_t)l * DMODEL * DMODEL,
        wk  + (size_t)l * DMODEL * DMODEL,
        wv  + (size_t)l * DMODEL * DMODEL,
        wo  + (size_t)l * DMODEL * DMODEL,
        wi  + (size_t)l * DFF * DMODEL,
        wof + (size_t)l * DMODEL * DFF,
        whi, wlo);

    // fused qkv projection (q columns pre-scaled by DH^-0.5)
    gemm128<128,32,2,2,4,4, 0,0,1><<<gqkv, 256, 0, stream>>>(
        xhi, xlo, whi + WQ_OFF, wlo + WQ_OFF,
        qkvhi, qkvlo, nullptr, nullptr, QKVLD, DMODEL, 0.125f);
    // attention (MFMA flash)
    attn_kernel<<<gattn, 256, 0, stream>>>(qkvhi, qkvlo, ohi, olo);
    // x = x + attn_out @ wo^T   (BK=64 swizzled: barrier-amortized, conflict-free)
    gemm128<64,64,1,4,4,2, 0,1,0><<<gwo, 256, 0, stream>>>(
        ohi, olo, whi + WO_OFF, wlo + WO_OFF,
        xhi, xlo, xhi, xlo, DMODEL, DMODEL, 1.f);
    // ff1 = relu(x @ wi^T)
    gemm128<128,32,2,2,4,4, 1,0,0><<<gwi, 256, 0, stream>>>(
        xhi, xlo, whi + WI_OFF, wlo + WI_OFF,
        fhi, flo, nullptr, nullptr, DFF, DMODEL, 1.f);
    // x = x + ff1 @ wof^T   (BK=64 swizzled)
    gemm128<64,64,1,4,4,2, 0,1,0><<<gwo, 256, 0, stream>>>(
        fhi, flo, whi + WOF_OFF, wlo + WOF_OFF,
        xhi, xlo, xhi, xlo, DMODEL, DFF, 1.f);
  }

  ln_kernel<<<MROWS, 256, 0, stream>>>(xhi, xlo, lnw, (float*)d_out);
}